// Round 15
// baseline (384.365 us; speedup 1.0000x reference)
//
#include <hip/hip_runtime.h>
#include <hip/hip_bf16.h>

#define L_SEQ 1024
#define DI    5120
#define DS    16
#define DR    160
#define NE    192      // DR + 2*DS
#define NC    16       // staging chunks (scan is single-sweep; NC only tiles LDS)
#define CL    64       // chunk length
#define SPLITK 16
#define KSPLIT (DI / SPLITK)   // 320
#define BK    64
#define LOG2E 1.44269504088896340736f

// workspace layout (bytes), non-overlapping
#define OFF_P     0                    // 12,582,912
#define OFF_XDBL  12582912             //    786,432
#define OFF_WH    13369344             //  1,638,400  dtw hi
#define OFF_WL    15007744             //  1,638,400  dtw lo
#define OFF_XH    16646144             //    393,216  xdbl hi
#define OFF_XL    17039360             //    393,216  xdbl lo
#define OFF_XPH   17432576             // 10,485,760  x hi
#define OFF_XPL   27918336             // 10,485,760  x lo
#define OFF_XWH   38404096             //  1,966,080  xw hi
#define OFF_XWL   40370176             //  1,966,080  xw lo
#define OFF_ZB    42336256             // 41,943,040  (delta,x) float2

typedef short s16x8 __attribute__((ext_vector_type(8)));
typedef float f32x4 __attribute__((ext_vector_type(4)));

__device__ __forceinline__ unsigned short bf_rn(float f) {
  unsigned u = __float_as_uint(f);
  u += 0x7FFFu + ((u >> 16) & 1u);
  return (unsigned short)(u >> 16);
}
__device__ __forceinline__ void split_hilo(float f, unsigned short& h, unsigned short& l) {
  h = bf_rn(f);
  float hf = __uint_as_float(((unsigned)h) << 16);
  l = bf_rn(f - hf);
}

// ---------------- generic cvt: f32 -> bf16 hi/lo planes
__global__ __launch_bounds__(256) void k_cvt(const float* __restrict__ src,
                                             unsigned short* __restrict__ hi,
                                             unsigned short* __restrict__ lo,
                                             int n4) {
  int i = blockIdx.x * 256 + threadIdx.x;
  if (i >= n4) return;
  int i4 = i * 4;
  float4 v = *(const float4*)&src[i4];
  float f[4] = {v.x, v.y, v.z, v.w};
  ushort4 h, l;
  unsigned short hh, ll;
  split_hilo(f[0], hh, ll); h.x = hh; l.x = ll;
  split_hilo(f[1], hh, ll); h.y = hh; l.y = ll;
  split_hilo(f[2], hh, ll); h.z = hh; l.z = ll;
  split_hilo(f[3], hh, ll); h.w = hh; l.w = ll;
  *(ushort4*)&hi[i4] = h;
  *(ushort4*)&lo[i4] = l;
}

// ---------------- GEMM1 (MFMA, preconverted planes)
#define AST2 72
__global__ __launch_bounds__(256) void k_xdbl_mfma2(const unsigned short* __restrict__ xph,
                                                    const unsigned short* __restrict__ xpl,
                                                    const unsigned short* __restrict__ wxh,
                                                    const unsigned short* __restrict__ wxl,
                                                    float* __restrict__ part) {
  __shared__ unsigned short sAh[64 * AST2];
  __shared__ unsigned short sAl[64 * AST2];
  const int tid  = threadIdx.x;
  const int lane = tid & 63;
  const int w    = tid >> 6;
  const int wl_  = w >> 1;
  const int we   = w & 1;
  const int l0   = blockIdx.y * 64;
  const int e0   = blockIdx.x * 64 + we * 32;
  const int kb   = blockIdx.z * KSPLIT;
  const int rc   = lane & 15;
  const int kg   = (lane >> 4) * 8;

  f32x4 acc[2][2] = {};
  for (int k0 = 0; k0 < KSPLIT; k0 += BK) {
    __syncthreads();
    for (int idx = tid; idx < 64 * 8; idx += 256) {
      int r = idx >> 3, c8 = (idx & 7) * 8;
      *(s16x8*)&sAh[r * AST2 + c8] = *(const s16x8*)&xph[(size_t)(l0 + r) * DI + kb + k0 + c8];
      *(s16x8*)&sAl[r * AST2 + c8] = *(const s16x8*)&xpl[(size_t)(l0 + r) * DI + kb + k0 + c8];
    }
    __syncthreads();
#pragma unroll
    for (int ks = 0; ks < BK; ks += 32) {
      s16x8 ah[2], al[2], bh[2], bl[2];
#pragma unroll
      for (int mf = 0; mf < 2; ++mf) {
        int row = wl_ * 32 + mf * 16 + rc;
        ah[mf] = *(const s16x8*)&sAh[row * AST2 + ks + kg];
        al[mf] = *(const s16x8*)&sAl[row * AST2 + ks + kg];
      }
#pragma unroll
      for (int nf = 0; nf < 2; ++nf) {
        size_t e = e0 + nf * 16 + rc;
        bh[nf] = *(const s16x8*)&wxh[e * DI + kb + k0 + ks + kg];
        bl[nf] = *(const s16x8*)&wxl[e * DI + kb + k0 + ks + kg];
      }
#pragma unroll
      for (int mf = 0; mf < 2; ++mf)
#pragma unroll
        for (int nf = 0; nf < 2; ++nf) {
          acc[mf][nf] = __builtin_amdgcn_mfma_f32_16x16x32_bf16(ah[mf], bh[nf], acc[mf][nf], 0, 0, 0);
          acc[mf][nf] = __builtin_amdgcn_mfma_f32_16x16x32_bf16(ah[mf], bl[nf], acc[mf][nf], 0, 0, 0);
          acc[mf][nf] = __builtin_amdgcn_mfma_f32_16x16x32_bf16(al[mf], bh[nf], acc[mf][nf], 0, 0, 0);
        }
    }
  }
#pragma unroll
  for (int mf = 0; mf < 2; ++mf)
#pragma unroll
    for (int nf = 0; nf < 2; ++nf)
#pragma unroll
      for (int r = 0; r < 4; ++r) {
        int l = l0 + wl_ * 32 + mf * 16 + (lane >> 4) * 4 + r;
        int e = e0 + nf * 16 + rc;
        part[((size_t)blockIdx.z * L_SEQ + l) * NE + e] = acc[mf][nf][r];
      }
}

// ---------------- reduce split-K partials; emit xdbl + bf16 planes
__global__ __launch_bounds__(256) void k_xdbl_reduce(const float* __restrict__ part,
                                                     float* __restrict__ xdbl,
                                                     unsigned short* __restrict__ xh,
                                                     unsigned short* __restrict__ xl) {
  int i4 = (blockIdx.x * 256 + threadIdx.x) * 4;   // grid=192
  float4 s = {0.f, 0.f, 0.f, 0.f};
#pragma unroll
  for (int z = 0; z < SPLITK; ++z) {
    float4 p = *(const float4*)&part[(size_t)z * L_SEQ * NE + i4];
    s.x += p.x; s.y += p.y; s.z += p.z; s.w += p.w;
  }
  *(float4*)&xdbl[i4] = s;
  float f[4] = {s.x, s.y, s.z, s.w};
  ushort4 h, l;
  unsigned short hh, ll;
  split_hilo(f[0], hh, ll); h.x = hh; l.x = ll;
  split_hilo(f[1], hh, ll); h.y = hh; l.y = ll;
  split_hilo(f[2], hh, ll); h.z = hh; l.z = ll;
  split_hilo(f[3], hh, ll); h.w = hh; l.w = ll;
  *(ushort4*)&xh[i4] = h;
  *(ushort4*)&xl[i4] = l;
}

// ---------------- GEMM2 (MFMA): writes interleaved zbuf[l][d] = (softplus, x)
#define AST 168
__global__ __launch_bounds__(512) void k_delta_mfma2(const unsigned short* __restrict__ xh,
                                                     const unsigned short* __restrict__ xl,
                                                     const unsigned short* __restrict__ wh,
                                                     const unsigned short* __restrict__ wlo,
                                                     const float* __restrict__ dtb,
                                                     const float* __restrict__ x,
                                                     float2* __restrict__ zbuf) {
  __shared__ unsigned short sAh[64 * AST];
  __shared__ unsigned short sAl[64 * AST];
  const int tid  = threadIdx.x;
  const int lane = tid & 63;
  const int w    = tid >> 6;
  const int wl_  = w >> 2;
  const int wd   = w & 3;
  const int l0   = blockIdx.y * 64;
  const int d0   = blockIdx.x * 128 + wd * 32;
  const int rc   = lane & 15;
  const int kg   = (lane >> 4) * 8;

  for (int idx = tid; idx < 64 * 20; idx += 512) {
    int r = idx / 20, c8 = (idx % 20) * 8;
    *(s16x8*)&sAh[r * AST + c8] = *(const s16x8*)&xh[(size_t)(l0 + r) * NE + c8];
    *(s16x8*)&sAl[r * AST + c8] = *(const s16x8*)&xl[(size_t)(l0 + r) * NE + c8];
  }
  __syncthreads();

  f32x4 acc[2][2] = {};
#pragma unroll
  for (int k0 = 0; k0 < DR; k0 += 32) {
    s16x8 ah[2], al[2], bh[2], bl[2];
#pragma unroll
    for (int mf = 0; mf < 2; ++mf) {
      int row = wl_ * 32 + mf * 16 + rc;
      ah[mf] = *(const s16x8*)&sAh[row * AST + k0 + kg];
      al[mf] = *(const s16x8*)&sAl[row * AST + k0 + kg];
    }
#pragma unroll
    for (int nf = 0; nf < 2; ++nf) {
      size_t d = d0 + nf * 16 + rc;
      bh[nf] = *(const s16x8*)&wh[d * DR + k0 + kg];
      bl[nf] = *(const s16x8*)&wlo[d * DR + k0 + kg];
    }
#pragma unroll
    for (int mf = 0; mf < 2; ++mf)
#pragma unroll
      for (int nf = 0; nf < 2; ++nf) {
        acc[mf][nf] = __builtin_amdgcn_mfma_f32_16x16x32_bf16(ah[mf], bh[nf], acc[mf][nf], 0, 0, 0);
        acc[mf][nf] = __builtin_amdgcn_mfma_f32_16x16x32_bf16(ah[mf], bl[nf], acc[mf][nf], 0, 0, 0);
        acc[mf][nf] = __builtin_amdgcn_mfma_f32_16x16x32_bf16(al[mf], bh[nf], acc[mf][nf], 0, 0, 0);
      }
  }
#pragma unroll
  for (int nf = 0; nf < 2; ++nf) {
    int d = d0 + nf * 16 + rc;
    float bias = dtb[d];
#pragma unroll
    for (int mf = 0; mf < 2; ++mf)
#pragma unroll
      for (int r = 0; r < 4; ++r) {
        int l = l0 + wl_ * 32 + mf * 16 + (lane >> 4) * 4 + r;
        float z = acc[mf][nf][r] + bias;
        float sp = fmaxf(z, 0.f) + __logf(1.f + __expf(-fabsf(z)));
        float xv = x[(size_t)l * DI + d];
        zbuf[(size_t)l * DI + d] = make_float2(sp, xv);
      }
  }
}

// ---------------- single-sweep scan: one block owns 64 d, walks all 1024 t
// grid 80, block 256 = 64 d x 4 ng; h carried in registers across the whole L.
// LDS: double-buffered (delta,x) tile + B/C tiles; staging overlaps compute.
__global__ __launch_bounds__(256) void k_scanS(const float2* __restrict__ zbuf,
                                               const float* __restrict__ xdbl,
                                               const float* __restrict__ A_log,
                                               const float* __restrict__ Dvec,
                                               float* __restrict__ out) {
  const int tid  = threadIdx.x;
  const int lane = tid & 63;
  const int w    = tid >> 6;
  const int dloc = w * 16 + (lane & 15);
  const int d    = blockIdx.x * 64 + dloc;
  const int ng   = lane >> 4;
  __shared__ __align__(16) float2 sZ[2][CL][64];   // 64KB
  __shared__ __align__(16) float  sB[2][CL][DS];   // 8KB
  __shared__ __align__(16) float  sC[2][CL][DS];   // 8KB

  float4 av = *(const float4*)&A_log[(size_t)d * DS + ng * 4];
  float aL[4] = {-__expf(av.x) * LOG2E, -__expf(av.y) * LOG2E,
                 -__expf(av.z) * LOG2E, -__expf(av.w) * LOG2E};
  float h[4] = {0.f, 0.f, 0.f, 0.f};
  const float Dv = Dvec[d];
  const size_t dbase = blockIdx.x * 64;

  // stage chunk 0 -> buf 0
  {
    const float2* zsrc = &zbuf[dbase];
    for (int i = tid; i < CL * 64; i += 256) {
      int t = i >> 6, dd = i & 63;
      sZ[0][t][dd] = zsrc[(size_t)t * DI + dd];
    }
    for (int i = tid; i < CL * DS; i += 256) {
      int t = i >> 4, n = i & 15;
      sB[0][t][n] = xdbl[(size_t)t * NE + DR + n];
      sC[0][t][n] = xdbl[(size_t)t * NE + DR + DS + n];
    }
  }
  __syncthreads();

  for (int c = 0; c < NC; ++c) {
    const int cur = c & 1;
    // issue next-chunk staging into the other buffer (overlaps compute)
    if (c + 1 < NC) {
      const int nxt = cur ^ 1;
      const float2* zsrc = &zbuf[(size_t)((c + 1) * CL) * DI + dbase];
      for (int i = tid; i < CL * 64; i += 256) {
        int t = i >> 6, dd = i & 63;
        sZ[nxt][t][dd] = zsrc[(size_t)t * DI + dd];
      }
      for (int i = tid; i < CL * DS; i += 256) {
        int t = i >> 4, n = i & 15;
        sB[nxt][t][n] = xdbl[(size_t)((c + 1) * CL + t) * NE + DR + n];
        sC[nxt][t][n] = xdbl[(size_t)((c + 1) * CL + t) * NE + DR + DS + n];
      }
    }
    // compute chunk c from buf cur (pure LDS)
    float* op = &out[(size_t)(c * CL) * DI + d];
#pragma unroll 4
    for (int t = 0; t < CL; ++t) {
      float2 z = sZ[cur][t][dloc];
      float dl = z.x, xv = z.y;
      float du = dl * xv;
      float4 b4 = *(const float4*)&sB[cur][t][ng * 4];
      float4 c4 = *(const float4*)&sC[cur][t][ng * 4];
      float bb[4] = {b4.x, b4.y, b4.z, b4.w};
      float cc[4] = {c4.x, c4.y, c4.z, c4.w};
      float yp0, yp1;
      {
        float dA0 = exp2f(dl * aL[0]);
        float dA1 = exp2f(dl * aL[1]);
        h[0] = dA0 * h[0] + du * bb[0];
        h[1] = dA1 * h[1] + du * bb[1];
        yp0 = h[0] * cc[0] + h[1] * cc[1];
      }
      {
        float dA2 = exp2f(dl * aL[2]);
        float dA3 = exp2f(dl * aL[3]);
        h[2] = dA2 * h[2] + du * bb[2];
        h[3] = dA3 * h[3] + du * bb[3];
        yp1 = h[2] * cc[2] + h[3] * cc[3];
      }
      float y = yp0 + yp1;
      y += __shfl_xor(y, 16, 64);
      y += __shfl_xor(y, 32, 64);
      if (ng == 0) op[(size_t)t * DI] = fmaf(xv, Dv, y);
    }
    __syncthreads();
  }
}

extern "C" void kernel_launch(void* const* d_in, const int* in_sizes, int n_in,
                              void* d_out, int out_size, void* d_ws, size_t ws_size,
                              hipStream_t stream) {
  const float* x     = (const float*)d_in[0];
  const float* A_log = (const float*)d_in[1];
  const float* Dvec  = (const float*)d_in[2];
  const float* xw    = (const float*)d_in[3];
  const float* dtw   = (const float*)d_in[4];
  const float* dtb   = (const float*)d_in[5];
  float* out = (float*)d_out;

  char* ws = (char*)d_ws;
  float* part  = (float*)(ws + OFF_P);
  float* xdbl  = (float*)(ws + OFF_XDBL);
  unsigned short* wh  = (unsigned short*)(ws + OFF_WH);
  unsigned short* wl  = (unsigned short*)(ws + OFF_WL);
  unsigned short* xh  = (unsigned short*)(ws + OFF_XH);
  unsigned short* xl  = (unsigned short*)(ws + OFF_XL);
  unsigned short* xph = (unsigned short*)(ws + OFF_XPH);
  unsigned short* xpl = (unsigned short*)(ws + OFF_XPL);
  unsigned short* wxh = (unsigned short*)(ws + OFF_XWH);
  unsigned short* wxl = (unsigned short*)(ws + OFF_XWL);
  float2* zbuf = (float2*)(ws + OFF_ZB);

  k_cvt<<<5120, 256, 0, stream>>>(x, xph, xpl, L_SEQ * DI / 4);
  k_cvt<<<960, 256, 0, stream>>>(xw, wxh, wxl, NE * DI / 4);
  k_cvt<<<800, 256, 0, stream>>>(dtw, wh, wl, DI * DR / 4);
  k_xdbl_mfma2<<<dim3(3, 16, SPLITK), 256, 0, stream>>>(xph, xpl, wxh, wxl, part);
  k_xdbl_reduce<<<192, 256, 0, stream>>>(part, xdbl, xh, xl);
  k_delta_mfma2<<<dim3(40, 16), 512, 0, stream>>>(xh, xl, wh, wl, dtb, x, zbuf);
  k_scanS<<<80, 256, 0, stream>>>(zbuf, xdbl, A_log, Dvec, out);
}

// Round 16
// 126.792 us; speedup vs baseline: 3.0315x; 3.0315x over previous
//
#include <hip/hip_runtime.h>
#include <hip/hip_bf16.h>

#define L_SEQ 1024
#define DI    5120
#define DS    16
#define DR    160
#define NE    192      // DR + 2*DS
#define NC    16       // scan chunks
#define CL    64       // chunk length = L_SEQ/NC
#define SPLITK 16
#define KSPLIT (DI / SPLITK)   // 320
#define BK    64
#define LOG2E 1.44269504088896340736f

// workspace layout (bytes), non-overlapping; ~95MB of ~256MB
#define OFF_P     0                    // 12,582,912
#define OFF_XDBL  12582912             //    786,432
#define OFF_WH    13369344             //  1,638,400  dtw hi
#define OFF_WL    15007744             //  1,638,400  dtw lo
#define OFF_XH    16646144             //    393,216  xdbl hi
#define OFF_XL    17039360             //    393,216  xdbl lo
#define OFF_XPH   17432576             // 10,485,760  x hi
#define OFF_XPL   27918336             // 10,485,760  x lo
#define OFF_XWH   38404096             //  1,966,080  xw hi
#define OFF_XWL   40370176             //  1,966,080  xw lo
#define OFF_ZB    42336256             // 41,943,040  (delta,x) float2
#define OFF_HEND  84279296             //  5,242,880
#define OFF_APROD 89522176             //  5,242,880

typedef short s16x8 __attribute__((ext_vector_type(8)));
typedef float f32x4 __attribute__((ext_vector_type(4)));

__device__ __forceinline__ unsigned short bf_rn(float f) {
  unsigned u = __float_as_uint(f);
  u += 0x7FFFu + ((u >> 16) & 1u);
  return (unsigned short)(u >> 16);
}
__device__ __forceinline__ void split_hilo(float f, unsigned short& h, unsigned short& l) {
  h = bf_rn(f);
  float hf = __uint_as_float(((unsigned)h) << 16);
  l = bf_rn(f - hf);
}

// ---------------- generic cvt: f32 -> bf16 hi/lo planes
__global__ __launch_bounds__(256) void k_cvt(const float* __restrict__ src,
                                             unsigned short* __restrict__ hi,
                                             unsigned short* __restrict__ lo,
                                             int n4) {
  int i = blockIdx.x * 256 + threadIdx.x;
  if (i >= n4) return;
  int i4 = i * 4;
  float4 v = *(const float4*)&src[i4];
  float f[4] = {v.x, v.y, v.z, v.w};
  ushort4 h, l;
  unsigned short hh, ll;
  split_hilo(f[0], hh, ll); h.x = hh; l.x = ll;
  split_hilo(f[1], hh, ll); h.y = hh; l.y = ll;
  split_hilo(f[2], hh, ll); h.z = hh; l.z = ll;
  split_hilo(f[3], hh, ll); h.w = hh; l.w = ll;
  *(ushort4*)&hi[i4] = h;
  *(ushort4*)&lo[i4] = l;
}

// ---------------- GEMM1 (MFMA, preconverted planes)
#define AST2 72
__global__ __launch_bounds__(256) void k_xdbl_mfma2(const unsigned short* __restrict__ xph,
                                                    const unsigned short* __restrict__ xpl,
                                                    const unsigned short* __restrict__ wxh,
                                                    const unsigned short* __restrict__ wxl,
                                                    float* __restrict__ part) {
  __shared__ unsigned short sAh[64 * AST2];
  __shared__ unsigned short sAl[64 * AST2];
  const int tid  = threadIdx.x;
  const int lane = tid & 63;
  const int w    = tid >> 6;
  const int wl_  = w >> 1;
  const int we   = w & 1;
  const int l0   = blockIdx.y * 64;
  const int e0   = blockIdx.x * 64 + we * 32;
  const int kb   = blockIdx.z * KSPLIT;
  const int rc   = lane & 15;
  const int kg   = (lane >> 4) * 8;

  f32x4 acc[2][2] = {};
  for (int k0 = 0; k0 < KSPLIT; k0 += BK) {
    __syncthreads();
    for (int idx = tid; idx < 64 * 8; idx += 256) {
      int r = idx >> 3, c8 = (idx & 7) * 8;
      *(s16x8*)&sAh[r * AST2 + c8] = *(const s16x8*)&xph[(size_t)(l0 + r) * DI + kb + k0 + c8];
      *(s16x8*)&sAl[r * AST2 + c8] = *(const s16x8*)&xpl[(size_t)(l0 + r) * DI + kb + k0 + c8];
    }
    __syncthreads();
#pragma unroll
    for (int ks = 0; ks < BK; ks += 32) {
      s16x8 ah[2], al[2], bh[2], bl[2];
#pragma unroll
      for (int mf = 0; mf < 2; ++mf) {
        int row = wl_ * 32 + mf * 16 + rc;
        ah[mf] = *(const s16x8*)&sAh[row * AST2 + ks + kg];
        al[mf] = *(const s16x8*)&sAl[row * AST2 + ks + kg];
      }
#pragma unroll
      for (int nf = 0; nf < 2; ++nf) {
        size_t e = e0 + nf * 16 + rc;
        bh[nf] = *(const s16x8*)&wxh[e * DI + kb + k0 + ks + kg];
        bl[nf] = *(const s16x8*)&wxl[e * DI + kb + k0 + ks + kg];
      }
#pragma unroll
      for (int mf = 0; mf < 2; ++mf)
#pragma unroll
        for (int nf = 0; nf < 2; ++nf) {
          acc[mf][nf] = __builtin_amdgcn_mfma_f32_16x16x32_bf16(ah[mf], bh[nf], acc[mf][nf], 0, 0, 0);
          acc[mf][nf] = __builtin_amdgcn_mfma_f32_16x16x32_bf16(ah[mf], bl[nf], acc[mf][nf], 0, 0, 0);
          acc[mf][nf] = __builtin_amdgcn_mfma_f32_16x16x32_bf16(al[mf], bh[nf], acc[mf][nf], 0, 0, 0);
        }
    }
  }
#pragma unroll
  for (int mf = 0; mf < 2; ++mf)
#pragma unroll
    for (int nf = 0; nf < 2; ++nf)
#pragma unroll
      for (int r = 0; r < 4; ++r) {
        int l = l0 + wl_ * 32 + mf * 16 + (lane >> 4) * 4 + r;
        int e = e0 + nf * 16 + rc;
        part[((size_t)blockIdx.z * L_SEQ + l) * NE + e] = acc[mf][nf][r];
      }
}

// ---------------- reduce split-K partials; emit xdbl + bf16 planes
__global__ __launch_bounds__(256) void k_xdbl_reduce(const float* __restrict__ part,
                                                     float* __restrict__ xdbl,
                                                     unsigned short* __restrict__ xh,
                                                     unsigned short* __restrict__ xl) {
  int i4 = (blockIdx.x * 256 + threadIdx.x) * 4;   // grid=192
  float4 s = {0.f, 0.f, 0.f, 0.f};
#pragma unroll
  for (int z = 0; z < SPLITK; ++z) {
    float4 p = *(const float4*)&part[(size_t)z * L_SEQ * NE + i4];
    s.x += p.x; s.y += p.y; s.z += p.z; s.w += p.w;
  }
  *(float4*)&xdbl[i4] = s;
  float f[4] = {s.x, s.y, s.z, s.w};
  ushort4 h, l;
  unsigned short hh, ll;
  split_hilo(f[0], hh, ll); h.x = hh; l.x = ll;
  split_hilo(f[1], hh, ll); h.y = hh; l.y = ll;
  split_hilo(f[2], hh, ll); h.z = hh; l.z = ll;
  split_hilo(f[3], hh, ll); h.w = hh; l.w = ll;
  *(ushort4*)&xh[i4] = h;
  *(ushort4*)&xl[i4] = l;
}

// ---------------- GEMM2 (MFMA): writes interleaved zbuf[l][d] = (softplus, x)
#define AST 168
__global__ __launch_bounds__(512) void k_delta_mfma2(const unsigned short* __restrict__ xh,
                                                     const unsigned short* __restrict__ xl,
                                                     const unsigned short* __restrict__ wh,
                                                     const unsigned short* __restrict__ wlo,
                                                     const float* __restrict__ dtb,
                                                     const float* __restrict__ x,
                                                     float2* __restrict__ zbuf) {
  __shared__ unsigned short sAh[64 * AST];
  __shared__ unsigned short sAl[64 * AST];
  const int tid  = threadIdx.x;
  const int lane = tid & 63;
  const int w    = tid >> 6;
  const int wl_  = w >> 2;
  const int wd   = w & 3;
  const int l0   = blockIdx.y * 64;
  const int d0   = blockIdx.x * 128 + wd * 32;
  const int rc   = lane & 15;
  const int kg   = (lane >> 4) * 8;

  for (int idx = tid; idx < 64 * 20; idx += 512) {
    int r = idx / 20, c8 = (idx % 20) * 8;
    *(s16x8*)&sAh[r * AST + c8] = *(const s16x8*)&xh[(size_t)(l0 + r) * NE + c8];
    *(s16x8*)&sAl[r * AST + c8] = *(const s16x8*)&xl[(size_t)(l0 + r) * NE + c8];
  }
  __syncthreads();

  f32x4 acc[2][2] = {};
#pragma unroll
  for (int k0 = 0; k0 < DR; k0 += 32) {
    s16x8 ah[2], al[2], bh[2], bl[2];
#pragma unroll
    for (int mf = 0; mf < 2; ++mf) {
      int row = wl_ * 32 + mf * 16 + rc;
      ah[mf] = *(const s16x8*)&sAh[row * AST + k0 + kg];
      al[mf] = *(const s16x8*)&sAl[row * AST + k0 + kg];
    }
#pragma unroll
    for (int nf = 0; nf < 2; ++nf) {
      size_t d = d0 + nf * 16 + rc;
      bh[nf] = *(const s16x8*)&wh[d * DR + k0 + kg];
      bl[nf] = *(const s16x8*)&wlo[d * DR + k0 + kg];
    }
#pragma unroll
    for (int mf = 0; mf < 2; ++mf)
#pragma unroll
      for (int nf = 0; nf < 2; ++nf) {
        acc[mf][nf] = __builtin_amdgcn_mfma_f32_16x16x32_bf16(ah[mf], bh[nf], acc[mf][nf], 0, 0, 0);
        acc[mf][nf] = __builtin_amdgcn_mfma_f32_16x16x32_bf16(ah[mf], bl[nf], acc[mf][nf], 0, 0, 0);
        acc[mf][nf] = __builtin_amdgcn_mfma_f32_16x16x32_bf16(al[mf], bh[nf], acc[mf][nf], 0, 0, 0);
      }
  }
#pragma unroll
  for (int nf = 0; nf < 2; ++nf) {
    int d = d0 + nf * 16 + rc;
    float bias = dtb[d];
#pragma unroll
    for (int mf = 0; mf < 2; ++mf)
#pragma unroll
      for (int r = 0; r < 4; ++r) {
        int l = l0 + wl_ * 32 + mf * 16 + (lane >> 4) * 4 + r;
        float z = acc[mf][nf][r] + bias;
        float sp = fmaxf(z, 0.f) + __logf(1.f + __expf(-fabsf(z)));
        float xv = x[(size_t)l * DI + d];
        zbuf[(size_t)l * DI + d] = make_float2(sp, xv);
      }
  }
}

// ---------------- scan pass 1: ng-split, PF=8, float2 zbuf
__global__ __launch_bounds__(256) void k_scan1f(const float2* __restrict__ zbuf,
                                                const float* __restrict__ xdbl,
                                                const float* __restrict__ A_log,
                                                float* __restrict__ hend,
                                                float* __restrict__ aprod) {
  const int lane = threadIdx.x & 63;
  const int w    = threadIdx.x >> 6;
  const int d    = blockIdx.x * 64 + w * 16 + (lane & 15);
  const int ng   = lane >> 4;
  const int c    = blockIdx.y;
  __shared__ __align__(16) float sB[CL][DS];
  for (int i = threadIdx.x; i < CL * DS; i += 256) {
    int t = i >> 4, n = i & 15;
    sB[t][n] = xdbl[(size_t)(c * CL + t) * NE + DR + n];
  }
  __syncthreads();
  float4 av = *(const float4*)&A_log[(size_t)d * DS + ng * 4];
  float aL[4] = {-__expf(av.x) * LOG2E, -__expf(av.y) * LOG2E,
                 -__expf(av.z) * LOG2E, -__expf(av.w) * LOG2E};
  float h[4] = {0.f, 0.f, 0.f, 0.f};
  float sdl = 0.f;
  const float2* zp = &zbuf[(size_t)(c * CL) * DI + d];
  float2 zb[8];
#pragma unroll
  for (int j = 0; j < 8; ++j) zb[j] = zp[(size_t)j * DI];
  for (int tt = 0; tt < CL; tt += 8) {
#pragma unroll
    for (int j = 0; j < 8; ++j) {
      float dl = zb[j].x, xv = zb[j].y;
      int tn = tt + 8 + j;
      if (tn < CL) zb[j] = zp[(size_t)tn * DI];
      float du = dl * xv;
      sdl += dl;
      float4 b4 = *(const float4*)&sB[tt + j][ng * 4];
      float bb[4] = {b4.x, b4.y, b4.z, b4.w};
#pragma unroll
      for (int q = 0; q < 4; ++q) {
        float dA = exp2f(dl * aL[q]);
        h[q] = dA * h[q] + du * bb[q];
      }
    }
  }
#pragma unroll
  for (int q = 0; q < 4; ++q) {
    int n = ng * 4 + q;
    hend[(size_t)(c * DS + n) * DI + d] = h[q];
    aprod[(size_t)(c * DS + n) * DI + d] = exp2f(aL[q] * sdl);
  }
}

// ---------------- scan pass 2: load-all-then-carry (in-place -> hstart)
__global__ __launch_bounds__(256) void k_scan2(float* __restrict__ hend,
                                               const float* __restrict__ aprod) {
  int i = blockIdx.x * 256 + threadIdx.x;   // 81920, grid=320
  float ap[NC], hv[NC];
#pragma unroll
  for (int c = 0; c < NC; ++c) {
    size_t idx = (size_t)c * DS * DI + i;
    ap[c] = aprod[idx];
    hv[c] = hend[idx];
  }
  float carry = 0.f;
#pragma unroll
  for (int c = 0; c < NC; ++c) {
    size_t idx = (size_t)c * DS * DI + i;
    hend[idx] = carry;
    carry = ap[c] * carry + hv[c];
  }
}

// ---------------- scan pass 3: ng-split, PF=8, float2 zbuf, emit y
__global__ __launch_bounds__(256) void k_scan3f(const float2* __restrict__ zbuf,
                                                const float* __restrict__ xdbl,
                                                const float* __restrict__ A_log,
                                                const float* __restrict__ Dvec,
                                                const float* __restrict__ hstart,
                                                float* __restrict__ out) {
  const int lane = threadIdx.x & 63;
  const int w    = threadIdx.x >> 6;
  const int d    = blockIdx.x * 64 + w * 16 + (lane & 15);
  const int ng   = lane >> 4;
  const int c    = blockIdx.y;
  __shared__ __align__(16) float sB[CL][DS];
  __shared__ __align__(16) float sC[CL][DS];
  for (int i = threadIdx.x; i < CL * DS; i += 256) {
    int t = i >> 4, n = i & 15;
    sB[t][n] = xdbl[(size_t)(c * CL + t) * NE + DR + n];
    sC[t][n] = xdbl[(size_t)(c * CL + t) * NE + DR + DS + n];
  }
  __syncthreads();
  float4 av = *(const float4*)&A_log[(size_t)d * DS + ng * 4];
  float aL[4] = {-__expf(av.x) * LOG2E, -__expf(av.y) * LOG2E,
                 -__expf(av.z) * LOG2E, -__expf(av.w) * LOG2E};
  float h[4];
#pragma unroll
  for (int q = 0; q < 4; ++q)
    h[q] = hstart[(size_t)(c * DS + ng * 4 + q) * DI + d];
  const float Dv = Dvec[d];
  const float2* zp = &zbuf[(size_t)(c * CL) * DI + d];
  float* op = &out[(size_t)(c * CL) * DI + d];
  float2 zb[8];
#pragma unroll
  for (int j = 0; j < 8; ++j) zb[j] = zp[(size_t)j * DI];
  for (int tt = 0; tt < CL; tt += 8) {
#pragma unroll
    for (int j = 0; j < 8; ++j) {
      float dl = zb[j].x, xv = zb[j].y;
      int tn = tt + 8 + j;
      if (tn < CL) zb[j] = zp[(size_t)tn * DI];
      float du = dl * xv;
      float4 b4 = *(const float4*)&sB[tt + j][ng * 4];
      float4 c4 = *(const float4*)&sC[tt + j][ng * 4];
      float bb[4] = {b4.x, b4.y, b4.z, b4.w};
      float cc[4] = {c4.x, c4.y, c4.z, c4.w};
      float y = 0.f;
#pragma unroll
      for (int q = 0; q < 4; ++q) {
        float dA = exp2f(dl * aL[q]);
        h[q] = dA * h[q] + du * bb[q];
        y += h[q] * cc[q];
      }
      y += __shfl_xor(y, 16, 64);
      y += __shfl_xor(y, 32, 64);
      if (ng == 0) op[(size_t)(tt + j) * DI] = fmaf(xv, Dv, y);
    }
  }
}

extern "C" void kernel_launch(void* const* d_in, const int* in_sizes, int n_in,
                              void* d_out, int out_size, void* d_ws, size_t ws_size,
                              hipStream_t stream) {
  const float* x     = (const float*)d_in[0];
  const float* A_log = (const float*)d_in[1];
  const float* Dvec  = (const float*)d_in[2];
  const float* xw    = (const float*)d_in[3];
  const float* dtw   = (const float*)d_in[4];
  const float* dtb   = (const float*)d_in[5];
  float* out = (float*)d_out;

  char* ws = (char*)d_ws;
  float* part  = (float*)(ws + OFF_P);
  float* xdbl  = (float*)(ws + OFF_XDBL);
  float* hend  = (float*)(ws + OFF_HEND);
  float* aprod = (float*)(ws + OFF_APROD);
  unsigned short* wh  = (unsigned short*)(ws + OFF_WH);
  unsigned short* wl  = (unsigned short*)(ws + OFF_WL);
  unsigned short* xh  = (unsigned short*)(ws + OFF_XH);
  unsigned short* xl  = (unsigned short*)(ws + OFF_XL);
  unsigned short* xph = (unsigned short*)(ws + OFF_XPH);
  unsigned short* xpl = (unsigned short*)(ws + OFF_XPL);
  unsigned short* wxh = (unsigned short*)(ws + OFF_XWH);
  unsigned short* wxl = (unsigned short*)(ws + OFF_XWL);
  float2* zbuf = (float2*)(ws + OFF_ZB);

  k_cvt<<<5120, 256, 0, stream>>>(x, xph, xpl, L_SEQ * DI / 4);
  k_cvt<<<960, 256, 0, stream>>>(xw, wxh, wxl, NE * DI / 4);
  k_cvt<<<800, 256, 0, stream>>>(dtw, wh, wl, DI * DR / 4);
  k_xdbl_mfma2<<<dim3(3, 16, SPLITK), 256, 0, stream>>>(xph, xpl, wxh, wxl, part);
  k_xdbl_reduce<<<192, 256, 0, stream>>>(part, xdbl, xh, xl);
  k_delta_mfma2<<<dim3(40, 16), 512, 0, stream>>>(xh, xl, wh, wl, dtb, x, zbuf);
  k_scan1f<<<dim3(80, NC), 256, 0, stream>>>(zbuf, xdbl, A_log, hend, aprod);
  k_scan2<<<320, 256, 0, stream>>>(hend, aprod);
  k_scan3f<<<dim3(80, NC), 256, 0, stream>>>(zbuf, xdbl, A_log, Dvec, hend, out);
}

// Round 17
// 121.602 us; speedup vs baseline: 3.1608x; 1.0427x over previous
//
#include <hip/hip_runtime.h>
#include <hip/hip_bf16.h>

#define L_SEQ 1024
#define DI    5120
#define DS    16
#define DR    160
#define NE    192      // DR + 2*DS
#define NC    32       // scan chunks
#define CL    32       // chunk length = L_SEQ/NC
#define SPLITK 16
#define KSPLIT (DI / SPLITK)   // 320
#define BK    64
#define LOG2E 1.44269504088896340736f

// workspace layout (bytes), non-overlapping; ~84MB of ~256MB
#define OFF_P     0                    // 12,582,912
#define OFF_XDBL  12582912             //    786,432
#define OFF_WH    13369344             //  1,638,400  dtw hi
#define OFF_WL    15007744             //  1,638,400  dtw lo
#define OFF_XH    16646144             //    393,216  xdbl hi
#define OFF_XL    17039360             //    393,216  xdbl lo
#define OFF_XPH   17432576             // 10,485,760  x hi
#define OFF_XPL   27918336             // 10,485,760  x lo
#define OFF_XWH   38404096             //  1,966,080  xw hi
#define OFF_XWL   40370176             //  1,966,080  xw lo
#define OFF_DELTA 42336256             // 20,971,520  f32 delta
#define OFF_HEND  63307776             // 10,485,760  (NC=32)
#define OFF_APROD 73793536             // 10,485,760

typedef short s16x8 __attribute__((ext_vector_type(8)));
typedef float f32x4 __attribute__((ext_vector_type(4)));

__device__ __forceinline__ unsigned short bf_rn(float f) {
  unsigned u = __float_as_uint(f);
  u += 0x7FFFu + ((u >> 16) & 1u);
  return (unsigned short)(u >> 16);
}
__device__ __forceinline__ void split_hilo(float f, unsigned short& h, unsigned short& l) {
  h = bf_rn(f);
  float hf = __uint_as_float(((unsigned)h) << 16);
  l = bf_rn(f - hf);
}

// ---------------- generic cvt: f32 -> bf16 hi/lo planes
__global__ __launch_bounds__(256) void k_cvt(const float* __restrict__ src,
                                             unsigned short* __restrict__ hi,
                                             unsigned short* __restrict__ lo,
                                             int n4) {
  int i = blockIdx.x * 256 + threadIdx.x;
  if (i >= n4) return;
  int i4 = i * 4;
  float4 v = *(const float4*)&src[i4];
  float f[4] = {v.x, v.y, v.z, v.w};
  ushort4 h, l;
  unsigned short hh, ll;
  split_hilo(f[0], hh, ll); h.x = hh; l.x = ll;
  split_hilo(f[1], hh, ll); h.y = hh; l.y = ll;
  split_hilo(f[2], hh, ll); h.z = hh; l.z = ll;
  split_hilo(f[3], hh, ll); h.w = hh; l.w = ll;
  *(ushort4*)&hi[i4] = h;
  *(ushort4*)&lo[i4] = l;
}

// ---------------- GEMM1 (MFMA, preconverted planes)
#define AST2 72
__global__ __launch_bounds__(256) void k_xdbl_mfma2(const unsigned short* __restrict__ xph,
                                                    const unsigned short* __restrict__ xpl,
                                                    const unsigned short* __restrict__ wxh,
                                                    const unsigned short* __restrict__ wxl,
                                                    float* __restrict__ part) {
  __shared__ unsigned short sAh[64 * AST2];
  __shared__ unsigned short sAl[64 * AST2];
  const int tid  = threadIdx.x;
  const int lane = tid & 63;
  const int w    = tid >> 6;
  const int wl_  = w >> 1;
  const int we   = w & 1;
  const int l0   = blockIdx.y * 64;
  const int e0   = blockIdx.x * 64 + we * 32;
  const int kb   = blockIdx.z * KSPLIT;
  const int rc   = lane & 15;
  const int kg   = (lane >> 4) * 8;

  f32x4 acc[2][2] = {};
  for (int k0 = 0; k0 < KSPLIT; k0 += BK) {
    __syncthreads();
    for (int idx = tid; idx < 64 * 8; idx += 256) {
      int r = idx >> 3, c8 = (idx & 7) * 8;
      *(s16x8*)&sAh[r * AST2 + c8] = *(const s16x8*)&xph[(size_t)(l0 + r) * DI + kb + k0 + c8];
      *(s16x8*)&sAl[r * AST2 + c8] = *(const s16x8*)&xpl[(size_t)(l0 + r) * DI + kb + k0 + c8];
    }
    __syncthreads();
#pragma unroll
    for (int ks = 0; ks < BK; ks += 32) {
      s16x8 ah[2], al[2], bh[2], bl[2];
#pragma unroll
      for (int mf = 0; mf < 2; ++mf) {
        int row = wl_ * 32 + mf * 16 + rc;
        ah[mf] = *(const s16x8*)&sAh[row * AST2 + ks + kg];
        al[mf] = *(const s16x8*)&sAl[row * AST2 + ks + kg];
      }
#pragma unroll
      for (int nf = 0; nf < 2; ++nf) {
        size_t e = e0 + nf * 16 + rc;
        bh[nf] = *(const s16x8*)&wxh[e * DI + kb + k0 + ks + kg];
        bl[nf] = *(const s16x8*)&wxl[e * DI + kb + k0 + ks + kg];
      }
#pragma unroll
      for (int mf = 0; mf < 2; ++mf)
#pragma unroll
        for (int nf = 0; nf < 2; ++nf) {
          acc[mf][nf] = __builtin_amdgcn_mfma_f32_16x16x32_bf16(ah[mf], bh[nf], acc[mf][nf], 0, 0, 0);
          acc[mf][nf] = __builtin_amdgcn_mfma_f32_16x16x32_bf16(ah[mf], bl[nf], acc[mf][nf], 0, 0, 0);
          acc[mf][nf] = __builtin_amdgcn_mfma_f32_16x16x32_bf16(al[mf], bh[nf], acc[mf][nf], 0, 0, 0);
        }
    }
  }
#pragma unroll
  for (int mf = 0; mf < 2; ++mf)
#pragma unroll
    for (int nf = 0; nf < 2; ++nf)
#pragma unroll
      for (int r = 0; r < 4; ++r) {
        int l = l0 + wl_ * 32 + mf * 16 + (lane >> 4) * 4 + r;
        int e = e0 + nf * 16 + rc;
        part[((size_t)blockIdx.z * L_SEQ + l) * NE + e] = acc[mf][nf][r];
      }
}

// ---------------- reduce split-K partials; emit xdbl + bf16 planes
__global__ __launch_bounds__(256) void k_xdbl_reduce(const float* __restrict__ part,
                                                     float* __restrict__ xdbl,
                                                     unsigned short* __restrict__ xh,
                                                     unsigned short* __restrict__ xl) {
  int i4 = (blockIdx.x * 256 + threadIdx.x) * 4;   // grid=192
  float4 s = {0.f, 0.f, 0.f, 0.f};
#pragma unroll
  for (int z = 0; z < SPLITK; ++z) {
    float4 p = *(const float4*)&part[(size_t)z * L_SEQ * NE + i4];
    s.x += p.x; s.y += p.y; s.z += p.z; s.w += p.w;
  }
  *(float4*)&xdbl[i4] = s;
  float f[4] = {s.x, s.y, s.z, s.w};
  ushort4 h, l;
  unsigned short hh, ll;
  split_hilo(f[0], hh, ll); h.x = hh; l.x = ll;
  split_hilo(f[1], hh, ll); h.y = hh; l.y = ll;
  split_hilo(f[2], hh, ll); h.z = hh; l.z = ll;
  split_hilo(f[3], hh, ll); h.w = hh; l.w = ll;
  *(ushort4*)&xh[i4] = h;
  *(ushort4*)&xl[i4] = l;
}

// ---------------- GEMM2 (MFMA, preconverted bf16): delta = softplus(dt·dtw^T + b)
#define AST 168
__global__ __launch_bounds__(512) void k_delta_mfma2(const unsigned short* __restrict__ xh,
                                                     const unsigned short* __restrict__ xl,
                                                     const unsigned short* __restrict__ wh,
                                                     const unsigned short* __restrict__ wlo,
                                                     const float* __restrict__ dtb,
                                                     float* __restrict__ delta) {
  __shared__ unsigned short sAh[64 * AST];
  __shared__ unsigned short sAl[64 * AST];
  const int tid  = threadIdx.x;
  const int lane = tid & 63;
  const int w    = tid >> 6;
  const int wl_  = w >> 2;
  const int wd   = w & 3;
  const int l0   = blockIdx.y * 64;
  const int d0   = blockIdx.x * 128 + wd * 32;
  const int rc   = lane & 15;
  const int kg   = (lane >> 4) * 8;

  for (int idx = tid; idx < 64 * 20; idx += 512) {
    int r = idx / 20, c8 = (idx % 20) * 8;
    *(s16x8*)&sAh[r * AST + c8] = *(const s16x8*)&xh[(size_t)(l0 + r) * NE + c8];
    *(s16x8*)&sAl[r * AST + c8] = *(const s16x8*)&xl[(size_t)(l0 + r) * NE + c8];
  }
  __syncthreads();

  f32x4 acc[2][2] = {};
#pragma unroll
  for (int k0 = 0; k0 < DR; k0 += 32) {
    s16x8 ah[2], al[2], bh[2], bl[2];
#pragma unroll
    for (int mf = 0; mf < 2; ++mf) {
      int row = wl_ * 32 + mf * 16 + rc;
      ah[mf] = *(const s16x8*)&sAh[row * AST + k0 + kg];
      al[mf] = *(const s16x8*)&sAl[row * AST + k0 + kg];
    }
#pragma unroll
    for (int nf = 0; nf < 2; ++nf) {
      size_t d = d0 + nf * 16 + rc;
      bh[nf] = *(const s16x8*)&wh[d * DR + k0 + kg];
      bl[nf] = *(const s16x8*)&wlo[d * DR + k0 + kg];
    }
#pragma unroll
    for (int mf = 0; mf < 2; ++mf)
#pragma unroll
      for (int nf = 0; nf < 2; ++nf) {
        acc[mf][nf] = __builtin_amdgcn_mfma_f32_16x16x32_bf16(ah[mf], bh[nf], acc[mf][nf], 0, 0, 0);
        acc[mf][nf] = __builtin_amdgcn_mfma_f32_16x16x32_bf16(ah[mf], bl[nf], acc[mf][nf], 0, 0, 0);
        acc[mf][nf] = __builtin_amdgcn_mfma_f32_16x16x32_bf16(al[mf], bh[nf], acc[mf][nf], 0, 0, 0);
      }
  }
#pragma unroll
  for (int nf = 0; nf < 2; ++nf) {
    int d = d0 + nf * 16 + rc;
    float bias = dtb[d];
#pragma unroll
    for (int mf = 0; mf < 2; ++mf)
#pragma unroll
      for (int r = 0; r < 4; ++r) {
        int l = l0 + wl_ * 32 + mf * 16 + (lane >> 4) * 4 + r;
        float z = acc[mf][nf][r] + bias;
        float sp = fmaxf(z, 0.f) + __logf(1.f + __expf(-fabsf(z)));
        delta[(size_t)l * DI + d] = sp;
      }
  }
}

// ---------------- scan pass 1 (R9 structure, NC=32): ng-split, PF=8
__global__ __launch_bounds__(256) void k_scan1(const float* __restrict__ x,
                                               const float* __restrict__ delta,
                                               const float* __restrict__ xdbl,
                                               const float* __restrict__ A_log,
                                               float* __restrict__ hend,
                                               float* __restrict__ aprod) {
  const int lane = threadIdx.x & 63;
  const int w    = threadIdx.x >> 6;
  const int d    = blockIdx.x * 64 + w * 16 + (lane & 15);
  const int ng   = lane >> 4;
  const int c    = blockIdx.y;
  __shared__ __align__(16) float sB[CL][DS];
  for (int i = threadIdx.x; i < CL * DS; i += 256) {
    int t = i >> 4, n = i & 15;
    sB[t][n] = xdbl[(size_t)(c * CL + t) * NE + DR + n];
  }
  __syncthreads();
  float4 av = *(const float4*)&A_log[(size_t)d * DS + ng * 4];
  float aL[4] = {-__expf(av.x) * LOG2E, -__expf(av.y) * LOG2E,
                 -__expf(av.z) * LOG2E, -__expf(av.w) * LOG2E};
  float h[4] = {0.f, 0.f, 0.f, 0.f};
  float sdl = 0.f;

  const float* dp = &delta[(size_t)(c * CL) * DI + d];
  const float* xp = &x[(size_t)(c * CL) * DI + d];
  float dlb[8], xvb[8];
#pragma unroll
  for (int j = 0; j < 8; ++j) { dlb[j] = dp[(size_t)j * DI]; xvb[j] = xp[(size_t)j * DI]; }
  for (int tt = 0; tt < CL; tt += 8) {
#pragma unroll
    for (int j = 0; j < 8; ++j) {
      float dl = dlb[j], xv = xvb[j];
      int tn = tt + 8 + j;
      if (tn < CL) { dlb[j] = dp[(size_t)tn * DI]; xvb[j] = xp[(size_t)tn * DI]; }
      float du = dl * xv;
      sdl += dl;
      float4 b4 = *(const float4*)&sB[tt + j][ng * 4];
      float bb[4] = {b4.x, b4.y, b4.z, b4.w};
#pragma unroll
      for (int q = 0; q < 4; ++q) {
        float dA = exp2f(dl * aL[q]);
        h[q] = dA * h[q] + du * bb[q];
      }
    }
  }
#pragma unroll
  for (int q = 0; q < 4; ++q) {
    int n = ng * 4 + q;
    hend[(size_t)(c * DS + n) * DI + d] = h[q];
    aprod[(size_t)(c * DS + n) * DI + d] = exp2f(aL[q] * sdl);
  }
}

// ---------------- scan pass 2: 32-chain load-all-then-carry (in-place -> hstart)
__global__ __launch_bounds__(256) void k_scan2(float* __restrict__ hend,
                                               const float* __restrict__ aprod) {
  int i = blockIdx.x * 256 + threadIdx.x;   // 81920, grid=320
  float ap[NC], hv[NC];
#pragma unroll
  for (int c = 0; c < NC; ++c) {
    size_t idx = (size_t)c * DS * DI + i;
    ap[c] = aprod[idx];
    hv[c] = hend[idx];
  }
  float carry = 0.f;
#pragma unroll
  for (int c = 0; c < NC; ++c) {
    size_t idx = (size_t)c * DS * DI + i;
    hend[idx] = carry;
    carry = ap[c] * carry + hv[c];
  }
}

// ---------------- scan pass 3 (R9 structure, NC=32): ng-split, PF=8, LDS-coalesced out
__global__ __launch_bounds__(256) void k_scan3(const float* __restrict__ x,
                                               const float* __restrict__ delta,
                                               const float* __restrict__ xdbl,
                                               const float* __restrict__ A_log,
                                               const float* __restrict__ Dvec,
                                               const float* __restrict__ hstart,
                                               float* __restrict__ out) {
  const int tid  = threadIdx.x;
  const int lane = tid & 63;
  const int w    = tid >> 6;
  const int d    = blockIdx.x * 64 + w * 16 + (lane & 15);
  const int ng   = lane >> 4;
  const int c    = blockIdx.y;
  __shared__ __align__(16) float sB[CL][DS];
  __shared__ __align__(16) float sC[CL][DS];
  __shared__ __align__(16) float sY[CL][64];
  for (int i = tid; i < CL * DS; i += 256) {
    int t = i >> 4, n = i & 15;
    sB[t][n] = xdbl[(size_t)(c * CL + t) * NE + DR + n];
    sC[t][n] = xdbl[(size_t)(c * CL + t) * NE + DR + DS + n];
  }
  __syncthreads();
  float4 av = *(const float4*)&A_log[(size_t)d * DS + ng * 4];
  float aL[4] = {-__expf(av.x) * LOG2E, -__expf(av.y) * LOG2E,
                 -__expf(av.z) * LOG2E, -__expf(av.w) * LOG2E};
  float h[4];
#pragma unroll
  for (int q = 0; q < 4; ++q)
    h[q] = hstart[(size_t)(c * DS + ng * 4 + q) * DI + d];
  const float Dv = Dvec[d];

  const float* dp = &delta[(size_t)(c * CL) * DI + d];
  const float* xp = &x[(size_t)(c * CL) * DI + d];
  float dlb[8], xvb[8];
#pragma unroll
  for (int j = 0; j < 8; ++j) { dlb[j] = dp[(size_t)j * DI]; xvb[j] = xp[(size_t)j * DI]; }
  for (int tt = 0; tt < CL; tt += 8) {
#pragma unroll
    for (int j = 0; j < 8; ++j) {
      float dl = dlb[j], xv = xvb[j];
      int tn = tt + 8 + j;
      if (tn < CL) { dlb[j] = dp[(size_t)tn * DI]; xvb[j] = xp[(size_t)tn * DI]; }
      float du = dl * xv;
      float4 b4 = *(const float4*)&sB[tt + j][ng * 4];
      float4 c4 = *(const float4*)&sC[tt + j][ng * 4];
      float bb[4] = {b4.x, b4.y, b4.z, b4.w};
      float cc[4] = {c4.x, c4.y, c4.z, c4.w};
      float y = 0.f;
#pragma unroll
      for (int q = 0; q < 4; ++q) {
        float dA = exp2f(dl * aL[q]);
        h[q] = dA * h[q] + du * bb[q];
        y += h[q] * cc[q];
      }
      y += __shfl_xor(y, 16, 64);
      y += __shfl_xor(y, 32, 64);
      if (ng == 0) sY[tt + j][w * 16 + (lane & 15)] = fmaf(xv, Dv, y);
    }
  }
  __syncthreads();
  // cooperative coalesced write: 32 rows x 64 f32, 256B contiguous per row
  for (int i = tid; i < CL * 16; i += 256) {
    int t = i >> 4, seg = i & 15;
    float4 v = *(const float4*)&sY[t][seg * 4];
    *(float4*)&out[(size_t)(c * CL + t) * DI + blockIdx.x * 64 + seg * 4] = v;
  }
}

extern "C" void kernel_launch(void* const* d_in, const int* in_sizes, int n_in,
                              void* d_out, int out_size, void* d_ws, size_t ws_size,
                              hipStream_t stream) {
  const float* x     = (const float*)d_in[0];
  const float* A_log = (const float*)d_in[1];
  const float* Dvec  = (const float*)d_in[2];
  const float* xw    = (const float*)d_in[3];
  const float* dtw   = (const float*)d_in[4];
  const float* dtb   = (const float*)d_in[5];
  float* out = (float*)d_out;

  char* ws = (char*)d_ws;
  float* part  = (float*)(ws + OFF_P);
  float* xdbl  = (float*)(ws + OFF_XDBL);
  float* delta = (float*)(ws + OFF_DELTA);
  float* hend  = (float*)(ws + OFF_HEND);
  float* aprod = (float*)(ws + OFF_APROD);
  unsigned short* wh  = (unsigned short*)(ws + OFF_WH);
  unsigned short* wl  = (unsigned short*)(ws + OFF_WL);
  unsigned short* xh  = (unsigned short*)(ws + OFF_XH);
  unsigned short* xl  = (unsigned short*)(ws + OFF_XL);
  unsigned short* xph = (unsigned short*)(ws + OFF_XPH);
  unsigned short* xpl = (unsigned short*)(ws + OFF_XPL);
  unsigned short* wxh = (unsigned short*)(ws + OFF_XWH);
  unsigned short* wxl = (unsigned short*)(ws + OFF_XWL);

  k_cvt<<<5120, 256, 0, stream>>>(x, xph, xpl, L_SEQ * DI / 4);
  k_cvt<<<960, 256, 0, stream>>>(xw, wxh, wxl, NE * DI / 4);
  k_cvt<<<800, 256, 0, stream>>>(dtw, wh, wl, DI * DR / 4);
  k_xdbl_mfma2<<<dim3(3, 16, SPLITK), 256, 0, stream>>>(xph, xpl, wxh, wxl, part);
  k_xdbl_reduce<<<192, 256, 0, stream>>>(part, xdbl, xh, xl);
  k_delta_mfma2<<<dim3(40, 16), 512, 0, stream>>>(xh, xl, wh, wl, dtb, delta);
  k_scan1<<<dim3(80, NC), 256, 0, stream>>>(x, delta, xdbl, A_log, hend, aprod);
  k_scan2<<<320, 256, 0, stream>>>(hend, aprod);
  k_scan3<<<dim3(80, NC), 256, 0, stream>>>(x, delta, xdbl, A_log, Dvec, hend, out);
}